// Round 6
// baseline (115.384 us; speedup 1.0000x reference)
//
#include <hip/hip_runtime.h>
#include <math.h>

// Reference: B=256; upsample 64/32/16 -> 256x256 (bilinear, align_corners=True), sum -> maps;
// 5x5 gaussian blur (sigma=4, reflect); per-sample max -> scores.
// d_out: [0:B] scores, [B:] maps (B*256*256).
//
// Structure: lane owns 4 consecutive columns -> one wave covers a full 256-wide row.
//  - rolling separable bilinear per column (y-state wave-uniform -> SGPR), LDS-staged inputs
//  - vertical 5-tap in a 4-deep register window
//  - horizontal 5-tap via 4 adjacent-lane shuffles (no LDS round-trip, no barriers)
//  - reflect boundary handled by WEIGHT FOLDING on interior rows/cols (no halo sampling)
//  - LDS pads are ZEROED (uninitialized pad * 0 weight gave NaN in round 5)
//  - maps stored once as float4; wave max -> d_ws partials; tiny deterministic reduce
// Pure function of inputs every call (graph-replay safe; no atomics, no init pass).

static constexpr int W     = 256;
static constexpr int QH    = 4;    // blocks per sample
static constexpr int WAVES = 4;    // waves per block
static constexpr int RW    = 16;   // rows owned per wave

__global__ __launch_bounds__(256, 4) void fused_kernel(
    const float* __restrict__ in0,   // [B,64,64]
    const float* __restrict__ in1,   // [B,32,32]
    const float* __restrict__ in2,   // [B,16,16]
    float* __restrict__ part,        // [B*QH*WAVES]
    float* __restrict__ maps)        // [B,256,256]
{
    const int t    = threadIdx.x;
    const int lane = t & 63;
    const int w    = t >> 6;
    const int bid  = blockIdx.x;
    const int b    = bid >> 2;
    const int R0   = (bid & 3) * (WAVES * RW) + w * RW;   // first owned row

    // Padded so x+1 / y+1 reads at the fx==0 / fy==0 edge stay in-bounds.
    // Pads MUST be zeroed: 0-weight taps still compute 0*(pad - a), NaN if pad is Inf/NaN.
    __shared__ float s0[64 * 64 + 68];
    __shared__ float s1[32 * 32 + 36];
    __shared__ float s2[16 * 16 + 20];

    // ---- stage inputs (float4) + zero pads ----
    {
        const float4* g0 = (const float4*)(in0 + (size_t)b * 4096);
        const float4* g1 = (const float4*)(in1 + (size_t)b * 1024);
        float4* l0 = (float4*)s0;
#pragma unroll
        for (int i = 0; i < 4; ++i) l0[t + i * 256] = g0[t + i * 256];
        ((float4*)s1)[t] = g1[t];
        if (t < 64) ((float4*)s2)[t] = ((const float4*)(in2 + (size_t)b * 256))[t];
        if (t < 68) s0[64 * 64 + t] = 0.0f;
        if (t < 36) s1[32 * 32 + t] = 0.0f;
        if (t < 20) s2[16 * 16 + t] = 0.0f;
    }
    __syncthreads();

    const float inv255 = 1.0f / 255.0f;

    // ---- per-column x params; lane owns cols c = 4*lane + j (xb = xa+1, padded) ----
    int xa0[4], xa1[4], xa2[4];
    float fx0[4], fx1[4], fx2[4];
#pragma unroll
    for (int j = 0; j < 4; ++j) {
        int c = 4 * lane + j;
        int ix = c * 63; int x0 = ix / 255; fx0[j] = (float)(ix - 255 * x0) * inv255; xa0[j] = x0;
        ix = c * 31; x0 = ix / 255; fx1[j] = (float)(ix - 255 * x0) * inv255; xa1[j] = x0;
        ix = c * 15; x0 = ix / 255; fx2[j] = (float)(ix - 255 * x0) * inv255; xa2[j] = x0;
    }

    // ---- gaussian weights (ksize=5, sigma=4) ----
    const float e1  = expf(-1.0f / 32.0f);
    const float e2  = expf(-4.0f / 32.0f);
    const float nrm = 1.0f + 2.0f * e1 + 2.0f * e2;
    const float wc = 1.0f / nrm, wa = e1 / nrm, wb = e2 / nrm;

    // ---- rolling bilinear state from row rs ----
    const int rs = max(R0 - 2, 0);
    const int re = min(R0 + RW + 1, 255);
    int ya, yb, yc, ra, rb, rc;
    float lo0[4], hi0[4], lo1[4], hi1[4], lo2[4], hi2[4];
    {
        int iy = rs * 63; ya = iy / 255; ra = iy - 255 * ya;
        iy = rs * 31; yb = iy / 255; rb = iy - 255 * yb;
        iy = rs * 15; yc = iy / 255; rc = iy - 255 * yc;
#pragma unroll
        for (int j = 0; j < 4; ++j) {
            float a, bb;
            a = s0[ya * 64 + xa0[j]]; bb = s0[ya * 64 + xa0[j] + 1]; lo0[j] = a + fx0[j] * (bb - a);
            a = s0[ya * 64 + 64 + xa0[j]]; bb = s0[ya * 64 + 64 + xa0[j] + 1]; hi0[j] = a + fx0[j] * (bb - a);
            a = s1[yb * 32 + xa1[j]]; bb = s1[yb * 32 + xa1[j] + 1]; lo1[j] = a + fx1[j] * (bb - a);
            a = s1[yb * 32 + 32 + xa1[j]]; bb = s1[yb * 32 + 32 + xa1[j] + 1]; hi1[j] = a + fx1[j] * (bb - a);
            a = s2[yc * 16 + xa2[j]]; bb = s2[yc * 16 + xa2[j] + 1]; lo2[j] = a + fx2[j] * (bb - a);
            a = s2[yc * 16 + 16 + xa2[j]]; bb = s2[yc * 16 + 16 + xa2[j] + 1]; hi2[j] = a + fx2[j] * (bb - a);
        }
    }

    float m0[4], m1[4], m2[4], m3[4], mn[4];
    float gmax = -INFINITY;

    // produce next map row into out[4], advance rolling state (wave-uniform branches)
    auto roll = [&](float out[4]) {
        const float f0 = (float)ra * inv255;
        const float f1 = (float)rb * inv255;
        const float f2 = (float)rc * inv255;
#pragma unroll
        for (int j = 0; j < 4; ++j)
            out[j] = (lo0[j] + f0 * (hi0[j] - lo0[j]))
                   + (lo1[j] + f1 * (hi1[j] - lo1[j]))
                   + (lo2[j] + f2 * (hi2[j] - lo2[j]));
        ra += 63;
        if (ra >= 255) {
            ra -= 255; ++ya;
#pragma unroll
            for (int j = 0; j < 4; ++j) {
                lo0[j] = hi0[j];
                float a = s0[(ya + 1) * 64 + xa0[j]], bb = s0[(ya + 1) * 64 + xa0[j] + 1];
                hi0[j] = a + fx0[j] * (bb - a);
            }
        }
        rb += 31;
        if (rb >= 255) {
            rb -= 255; ++yb;
#pragma unroll
            for (int j = 0; j < 4; ++j) {
                lo1[j] = hi1[j];
                float a = s1[(yb + 1) * 32 + xa1[j]], bb = s1[(yb + 1) * 32 + xa1[j] + 1];
                hi1[j] = a + fx1[j] * (bb - a);
            }
        }
        rc += 15;
        if (rc >= 255) {
            rc -= 255; ++yc;
#pragma unroll
            for (int j = 0; j < 4; ++j) {
                lo2[j] = hi2[j];
                float a = s2[(yc + 1) * 16 + xa2[j]], bb = s2[(yc + 1) * 16 + xa2[j] + 1];
                hi2[j] = a + fx2[j] * (bb - a);
            }
        }
    };

    // horizontal 5-tap (reflect at x edges via weight fold) + running max
    auto hmax = [&](const float vv[4]) {
        float l1 = __shfl_up(vv[3], 1);    // col-1
        float l2 = __shfl_up(vv[2], 1);    // col-2
        float r1 = __shfl_down(vv[0], 1);  // col+4
        float r2 = __shfl_down(vv[1], 1);  // col+5
        if (lane == 0)  { l1 = vv[1]; l2 = vv[2]; }
        if (lane == 63) { r1 = vv[2]; r2 = vv[1]; }
        float o0 = wc * vv[0] + wa * (l1 + vv[1])    + wb * (l2 + vv[2]);
        float o1 = wc * vv[1] + wa * (vv[0] + vv[2]) + wb * (l1 + vv[3]);
        float o2 = wc * vv[2] + wa * (vv[1] + vv[3]) + wb * (vv[0] + r1);
        float o3 = wc * vv[3] + wa * (vv[2] + r1)    + wb * (vv[1] + r2);
        gmax = fmaxf(gmax, fmaxf(fmaxf(o0, o1), fmaxf(o2, o3)));
    };

    float* __restrict__ mrow = maps + (size_t)b * W * W + 4 * lane;
    auto store_row = [&](int r, const float v[4]) {
        *(float4*)(mrow + (size_t)r * W) = make_float4(v[0], v[1], v[2], v[3]);
    };

    // ---- prologue: prime window with rows rs..rs+3 ----
    roll(m0); roll(m1); roll(m2); roll(m3);
    if (R0 == 0) {
        store_row(0, m0); store_row(1, m1); store_row(2, m2); store_row(3, m3);
        float v[4];
#pragma unroll
        for (int j = 0; j < 4; ++j) v[j] = wc * m0[j] + 2.0f * wa * m1[j] + 2.0f * wb * m2[j];
        hmax(v);                                     // output row 0 (reflect fold)
#pragma unroll
        for (int j = 0; j < 4; ++j) v[j] = wa * (m0[j] + m2[j]) + (wc + wb) * m1[j] + wb * m3[j];
        hmax(v);                                     // output row 1
    } else {
        store_row(R0, m2); store_row(R0 + 1, m3);
    }

    // ---- main loop, branch-free body; split store/no-store ----
    for (int rn = rs + 4; rn <= R0 + RW - 1; ++rn) {
        roll(mn);
        store_row(rn, mn);
        float v[4];
#pragma unroll
        for (int j = 0; j < 4; ++j) {
            v[j] = wb * (m0[j] + mn[j]) + wa * (m1[j] + m3[j]) + wc * m2[j];
            m0[j] = m1[j]; m1[j] = m2[j]; m2[j] = m3[j]; m3[j] = mn[j];
        }
        hmax(v);
    }
    for (int rn = R0 + RW; rn <= re; ++rn) {         // rows computed for vertical halo only
        roll(mn);
        float v[4];
#pragma unroll
        for (int j = 0; j < 4; ++j) {
            v[j] = wb * (m0[j] + mn[j]) + wa * (m1[j] + m3[j]) + wc * m2[j];
            m0[j] = m1[j]; m1[j] = m2[j]; m2[j] = m3[j]; m3[j] = mn[j];
        }
        hmax(v);
    }
    if (R0 == W - RW) {                              // bottom edge folds (window = rows 252..255)
        float v[4];
#pragma unroll
        for (int j = 0; j < 4; ++j) v[j] = wb * m0[j] + wa * (m1[j] + m3[j]) + (wc + wb) * m2[j];
        hmax(v);                                     // output row 254
#pragma unroll
        for (int j = 0; j < 4; ++j) v[j] = 2.0f * wb * m1[j] + 2.0f * wa * m2[j] + wc * m3[j];
        hmax(v);                                     // output row 255
    }

    // ---- wave max -> partial ----
#pragma unroll
    for (int off = 32; off > 0; off >>= 1)
        gmax = fmaxf(gmax, __shfl_down(gmax, off));
    if (lane == 0) part[bid * WAVES + w] = gmax;
}

__global__ void reduce_kernel(const float* __restrict__ part,
                              float* __restrict__ scores, int B) {
    int i = blockIdx.x * blockDim.x + threadIdx.x;
    if (i < B) {
        const int P = QH * WAVES;   // 16 consecutive partials per sample
        float m = part[P * i];
#pragma unroll
        for (int k = 1; k < P; ++k) m = fmaxf(m, part[P * i + k]);
        scores[i] = m;
    }
}

extern "C" void kernel_launch(void* const* d_in, const int* in_sizes, int n_in,
                              void* d_out, int out_size, void* d_ws, size_t ws_size,
                              hipStream_t stream) {
    const float* in0 = (const float*)d_in[0];
    const float* in1 = (const float*)d_in[1];
    const float* in2 = (const float*)d_in[2];
    const int B = in_sizes[0] / (64 * 64);

    float* scores = (float*)d_out;
    float* maps   = (float*)d_out + B;
    float* part   = (float*)d_ws;           // B*16 floats, fully rewritten each call

    hipLaunchKernelGGL(fused_kernel, dim3(B * QH), dim3(256), 0, stream,
                       in0, in1, in2, part, maps);
    hipLaunchKernelGGL(reduce_kernel, dim3((B + 255) / 256), dim3(256), 0, stream,
                       part, scores, B);
}